// Round 4
// baseline (1216.252 us; speedup 1.0000x reference)
//
#include <hip/hip_runtime.h>
#include <cstdint>

#define HDIM 64
#define BKT 98        // buckets of 1024 nodes (dst >> 10)
#define BSHIFT 10
#define BCAP 36864    // slots/bucket: mean 32768, +22 sigma margin
#define CHUNK 128     // LDS bin capacity; slice/bins mean ~64

// ---------------- detect edge dtype (int64 vs int32) + zero tails ----------------
__global__ void k_detect(const unsigned* ei, int* flag, int* tails) {
    __shared__ int ok;
    int t = threadIdx.x;
    if (t == 0) ok = 1;
    if (t < BKT) tails[t] = 0;
    __syncthreads();
    // int64 edge values < 2^31 => every odd 4B word of first 256 words is 0
    if (t < 128 && ei[2 * t + 1] != 0u) ok = 0;   // benign race: all writers store 0
    __syncthreads();
    if (t == 0) *flag = ok;
}

__device__ __forceinline__ int edge_val(const void* ei, int is64, long long idx) {
    if (is64) return (int)((const long long*)ei)[idx];
    return ((const int*)ei)[idx];
}

// ---------------- multisplit: one LDS binning phase + one drain phase ----------------
// Block owns a contiguous slice (~6250 edges); bins hold the whole slice
// (mean 64/bin, cap 128, global-reserve fallback preserves correctness).
// packed val = (dst_local(10b) << 17) | src(17b).
__global__ __launch_bounds__(1024) void k_bucket(const void* ei, const int* flag,
                                                 int* tails, unsigned* packed, int E) {
    __shared__ int bincnt[BKT];
    __shared__ unsigned binbuf[BKT][CHUNK];
    int tid = threadIdx.x;
    int lane = tid & 63, wid = tid >> 6;   // 16 waves
    for (int i = tid; i < BKT; i += 1024) bincnt[i] = 0;
    __syncthreads();
    int is64 = *flag;
    int per = (E + gridDim.x - 1) / gridDim.x;
    int e0 = blockIdx.x * per;
    int e1 = min(E, e0 + per);
    for (int e = e0 + tid; e < e1; e += 1024) {
        int d = edge_val(ei, is64, (long long)E + e);
        int s = edge_val(ei, is64, (long long)e);
        int b = d >> BSHIFT;
        unsigned val = ((unsigned)(d & 1023) << 17) | (unsigned)s;
        int pos = atomicAdd(&bincnt[b], 1);
        if (pos < CHUNK) binbuf[b][pos] = val;
        else {                                   // rare overflow: direct global slot
            int p = atomicAdd(&tails[b], 1);
            if (p < BCAP) packed[(size_t)b * BCAP + p] = val;
        }
    }
    __syncthreads();
    for (int b = wid; b < BKT; b += 16) {        // drain: wave-private bins
        int c = min(bincnt[b], CHUNK);
        if (c > 0) {
            int gbase = 0;
            if (lane == 0) gbase = atomicAdd(&tails[b], c);
            gbase = __shfl(gbase, 0);
            for (int k = lane; k < c; k += 64) {
                int p = gbase + k;
                if (p < BCAP) packed[(size_t)b * BCAP + p] = binbuf[b][k];
            }
        }
    }
}

// ---------------- bucket_base = exclusive prefix of tails (parallel) ----------------
__global__ void k_base(const int* tails, int* bucket_base, int* rowptr, int N_) {
    __shared__ int sm[128];
    int t = threadIdx.x;
    int v = 0;
    if (t < BKT) { v = tails[t]; if (v > BCAP) v = BCAP; }
    sm[t] = v;
    __syncthreads();
    for (int off = 1; off < 128; off <<= 1) {
        int u = (t >= off) ? sm[t - off] : 0;
        __syncthreads();
        sm[t] += u;
        __syncthreads();
    }
    if (t <= BKT) bucket_base[t] = sm[t] - ((t < BKT) ? v : (sm[t] - sm[t - 1]));
    if (t < BKT) bucket_base[t] = sm[t] - v;          // exclusive
    if (t == BKT) { bucket_base[BKT] = sm[BKT - 1]; rowptr[N_] = sm[BKT - 1]; }
}

// ---------------- per-bucket CSR build: LDS histogram + scan + scatter ----------------
__global__ __launch_bounds__(1024) void k_build(const unsigned* packed, const int* tails,
                                                const int* bucket_base, int* rowptr,
                                                float* dis, int* col, int N_) {
    __shared__ int cnt[1024];
    __shared__ int pfx[1024];
    __shared__ int fill[1024];
    int b = blockIdx.x, tid = threadIdx.x;
    int nb_ = tails[b]; if (nb_ > BCAP) nb_ = BCAP;
    const unsigned* pb = packed + (size_t)b * BCAP;
    cnt[tid] = 0; fill[tid] = 0;
    __syncthreads();
    for (int s = tid; s < nb_; s += 1024)
        atomicAdd(&cnt[pb[s] >> 17], 1);
    __syncthreads();
    int v = cnt[tid];
    pfx[tid] = v;
    __syncthreads();
    for (int off = 1; off < 1024; off <<= 1) {
        int t = (tid >= off) ? pfx[tid - off] : 0;
        __syncthreads();
        pfx[tid] += t;
        __syncthreads();
    }
    int excl = pfx[tid] - v;
    int rowbase = bucket_base[b];
    int node = (b << BSHIFT) + tid;
    if (node < N_) {
        rowptr[node] = rowbase + excl;
        dis[node] = rsqrtf((float)(v + 1));
    }
    cnt[tid] = rowbase + excl;
    __syncthreads();
    for (int s = tid; s < nb_; s += 1024) {
        unsigned vv = pb[s];
        int dl = vv >> 17;
        int pos = cnt[dl] + atomicAdd(&fill[dl], 1);   // LDS atomic only
        col[pos] = (int)(vv & 131071u);
    }
}

// ---------------- g = dis[i] * (in @ W)   [N,K]@[K,64] ----------------
// W transposed+XOR-swizzled in LDS: one ds_read_b128 feeds 16 FMAs (4 rows).
template <int K>
__global__ __launch_bounds__(256) void k_gemm_scale(const float* __restrict__ in,
                                                    const float* __restrict__ W,
                                                    const float* __restrict__ dis,
                                                    float* __restrict__ g, int n) {
    __shared__ float wt[64 * K];
    for (int i = threadIdx.x; i < K * 64; i += 256) {
        int f = i & 63, k = i >> 6;
        int k4 = k >> 2, j = k & 3;
        wt[f * K + (((k4 ^ (f & 15)) << 2) | j)] = W[i];   // W[k][f] -> wt[f][swz(k)]
    }
    __syncthreads();
    int lane = threadIdx.x & 63;
    int wid = threadIdx.x >> 6;                  // 4 waves; wave handles 16 rows
    const float* wtl = wt + lane * K;
    int sw = lane & 15;
    int r00 = blockIdx.x * 64 + wid * 16;
    for (int i4 = 0; i4 < 4; i4++) {             // 4 quads of 4 rows
        int r0 = r00 + i4 * 4;
        if (r0 >= n) break;
        float a0 = 0.f, a1 = 0.f, a2 = 0.f, a3 = 0.f;
        const float4* x0 = (const float4*)(in + (size_t)r0 * K);
        const float4* x1 = (const float4*)(in + (size_t)(r0 + 1) * K);
        const float4* x2 = (const float4*)(in + (size_t)(r0 + 2) * K);
        const float4* x3 = (const float4*)(in + (size_t)(r0 + 3) * K);
        bool g1 = r0 + 1 < n, g2 = r0 + 2 < n, g3 = r0 + 3 < n;
#pragma unroll
        for (int k4 = 0; k4 < K / 4; k4++) {
            float4 wv = *(const float4*)(wtl + ((k4 ^ sw) << 2));
            float4 xv0 = x0[k4];
            a0 = fmaf(xv0.x, wv.x, a0); a0 = fmaf(xv0.y, wv.y, a0);
            a0 = fmaf(xv0.z, wv.z, a0); a0 = fmaf(xv0.w, wv.w, a0);
            if (g1) { float4 xv = x1[k4];
                a1 = fmaf(xv.x, wv.x, a1); a1 = fmaf(xv.y, wv.y, a1);
                a1 = fmaf(xv.z, wv.z, a1); a1 = fmaf(xv.w, wv.w, a1); }
            if (g2) { float4 xv = x2[k4];
                a2 = fmaf(xv.x, wv.x, a2); a2 = fmaf(xv.y, wv.y, a2);
                a2 = fmaf(xv.z, wv.z, a2); a2 = fmaf(xv.w, wv.w, a2); }
            if (g3) { float4 xv = x3[k4];
                a3 = fmaf(xv.x, wv.x, a3); a3 = fmaf(xv.y, wv.y, a3);
                a3 = fmaf(xv.z, wv.z, a3); a3 = fmaf(xv.w, wv.w, a3); }
        }
        g[(size_t)r0 * HDIM + lane] = a0 * dis[r0];
        if (g1) g[(size_t)(r0 + 1) * HDIM + lane] = a1 * dis[r0 + 1];
        if (g2) g[(size_t)(r0 + 2) * HDIM + lane] = a2 * dis[r0 + 2];
        if (g3) g[(size_t)(r0 + 3) * HDIM + lane] = a3 * dis[r0 + 3];
    }
}

// ---------------- out[d] = [relu]( dis[d]*(g[d] + sum_e g[col[e]]) + b ) ----------
template <bool RELU>
__global__ __launch_bounds__(256) void k_aggregate(const float* __restrict__ g,
                                                   const int* __restrict__ rowptr,
                                                   const int* __restrict__ col,
                                                   const float* __restrict__ dis,
                                                   const float* __restrict__ bias,
                                                   float* __restrict__ out, int n) {
    int lane = threadIdx.x & 63;
    int wid = threadIdx.x >> 6;
    int node = blockIdx.x * (blockDim.x >> 6) + wid;
    if (node >= n) return;
    float s = g[(size_t)node * HDIM + lane];
    int e = rowptr[node], end = rowptr[node + 1];
    for (; e + 7 < end; e += 8) {
        int c0 = col[e], c1 = col[e + 1], c2 = col[e + 2], c3 = col[e + 3];
        int c4 = col[e + 4], c5 = col[e + 5], c6 = col[e + 6], c7 = col[e + 7];
        float v0 = g[(size_t)c0 * HDIM + lane];
        float v1 = g[(size_t)c1 * HDIM + lane];
        float v2 = g[(size_t)c2 * HDIM + lane];
        float v3 = g[(size_t)c3 * HDIM + lane];
        float v4 = g[(size_t)c4 * HDIM + lane];
        float v5 = g[(size_t)c5 * HDIM + lane];
        float v6 = g[(size_t)c6 * HDIM + lane];
        float v7 = g[(size_t)c7 * HDIM + lane];
        s += ((v0 + v1) + (v2 + v3)) + ((v4 + v5) + (v6 + v7));
    }
    for (; e < end; e++) s += g[(size_t)col[e] * HDIM + lane];
    float o = fmaf(dis[node], s, bias[lane]);
    if (RELU) o = fmaxf(o, 0.f);
    out[(size_t)node * HDIM + lane] = o;
}

extern "C" void kernel_launch(void* const* d_in, const int* in_sizes, int n_in,
                              void* d_out, int out_size, void* d_ws, size_t ws_size,
                              hipStream_t stream) {
    const float* x  = (const float*)d_in[0];
    const void*  ei = d_in[1];
    const float* W1 = (const float*)d_in[2];
    const float* b1 = (const float*)d_in[3];
    const float* W2 = (const float*)d_in[4];
    const float* b2 = (const float*)d_in[5];
    const float* W3 = (const float*)d_in[6];
    const float* b3 = (const float*)d_in[7];
    float* out = (float*)d_out;

    const int N = in_sizes[0] / 128;   // 100000
    const int E = in_sizes[1] / 2;     // 3200000

    char* ws = (char*)d_ws;
    auto alloc = [&](size_t bytes) {
        char* p = ws;
        ws += ((bytes + 255) / 256) * 256;
        return p;
    };
    int*   flag   = (int*)alloc(4);
    int*   tails  = (int*)alloc(BKT * 4);
    int*   bbase  = (int*)alloc((BKT + 1) * 4);
    int*   rowptr = (int*)alloc((size_t)(N + 1) * 4);
    float* dis    = (float*)alloc((size_t)N * 4);
    int*   col    = (int*)alloc((size_t)E * 4);
    float* bufA   = (float*)alloc((size_t)N * HDIM * 4);
    float* bufB   = (float*)alloc((size_t)N * HDIM * 4);
    unsigned* packed = (unsigned*)bufA;   // 98*36864*4 = 14.45 MB <= 25.6 MB

    k_detect<<<1, 128, 0, stream>>>((const unsigned*)ei, flag, tails);
    k_bucket<<<512, 1024, 0, stream>>>(ei, flag, tails, packed, E);
    k_base<<<1, 128, 0, stream>>>(tails, bbase, rowptr, N);
    k_build<<<BKT, 1024, 0, stream>>>(packed, tails, bbase, rowptr, dis, col, N);

    const int gemmGrid = (N + 63) / 64;
    const int aggGrid = (N + 3) / 4;

    k_gemm_scale<128><<<gemmGrid, 256, 0, stream>>>(x, W1, dis, bufA, N);
    k_aggregate<true><<<aggGrid, 256, 0, stream>>>(bufA, rowptr, col, dis, b1, bufB, N);
    k_gemm_scale<64><<<gemmGrid, 256, 0, stream>>>(bufB, W2, dis, bufA, N);
    k_aggregate<true><<<aggGrid, 256, 0, stream>>>(bufA, rowptr, col, dis, b2, bufB, N);
    k_gemm_scale<64><<<gemmGrid, 256, 0, stream>>>(bufB, W3, dis, bufA, N);
    k_aggregate<false><<<aggGrid, 256, 0, stream>>>(bufA, rowptr, col, dis, b3, out, N);
}

// Round 5
// 734.088 us; speedup vs baseline: 1.6568x; 1.6568x over previous
//
#include <hip/hip_runtime.h>
#include <cstdint>

#define HDIM 64
#define BKT 98        // buckets of 1024 nodes (dst >> 10), id fits 7 bits
#define BSHIFT 10
#define BCAP 36864    // slots/bucket: mean 32653, +23 sigma margin

// ---------------- detect edge dtype (int64 vs int32) + zero tails ----------------
__global__ void k_detect(const unsigned* ei, int* flag, int* tails) {
    __shared__ int ok;
    int t = threadIdx.x;
    if (t == 0) ok = 1;
    if (t < BKT) tails[t] = 0;
    __syncthreads();
    if (t < 128 && ei[2 * t + 1] != 0u) ok = 0;   // benign race: all writers store 0
    __syncthreads();
    if (t == 0) *flag = ok;
}

__device__ __forceinline__ int edge_val(const void* ei, int is64, long long idx) {
    if (is64) return (int)((const long long*)ei)[idx];
    return ((const int*)ei)[idx];
}

// ---------------- multisplit via 7-ballot match-mask (no per-edge atomics) --------
// packed val = (dst_local(10b) << 17) | src(17b). Per wave: lanes with equal
// bucket form a group (7 ballots); leader stores group count in wcnt; block
// reduce -> one global atomic per bucket per block.
__global__ __launch_bounds__(1024) void k_bucket(const void* ei, const int* flag,
                                                 int* tails, unsigned* packed, int E) {
    __shared__ int wcnt[16][BKT];
    __shared__ int wbase[16][BKT];
    int tid = threadIdx.x;
    int lane = tid & 63, wid = tid >> 6;     // 16 waves
    for (int i = tid; i < 16 * BKT; i += 1024) ((int*)wcnt)[i] = 0;
    __syncthreads();
    int is64 = *flag;
    int e = blockIdx.x * 1024 + tid;
    int b = -1; unsigned val = 0;
    if (e < E) {
        int d = edge_val(ei, is64, (long long)E + e);
        int s = edge_val(ei, is64, (long long)e);
        b = d >> BSHIFT;
        val = ((unsigned)(d & 1023) << 17) | (unsigned)s;
    }
    // match-mask over 7-bit bucket id (invalid lanes read as id=127 != any valid)
    unsigned long long m = ~0ull;
#pragma unroll
    for (int bit = 0; bit < 7; bit++) {
        unsigned long long bb = __ballot(((unsigned)b >> bit) & 1);
        m &= ((((unsigned)b >> bit) & 1) ? bb : ~bb);
    }
    unsigned long long below = (lane == 0) ? 0ull : ((~0ull) >> (64 - lane));
    int rank = __popcll(m & below);
    if (b >= 0 && rank == 0) wcnt[wid][b] = __popcll(m);   // unique writer
    __syncthreads();
    if (tid < BKT) {
        int tot = 0;
        int pw[16];
#pragma unroll
        for (int w = 0; w < 16; w++) { pw[w] = tot; tot += wcnt[w][tid]; }
        int gb = (tot > 0) ? atomicAdd(&tails[tid], tot) : 0;
#pragma unroll
        for (int w = 0; w < 16; w++) wbase[w][tid] = gb + pw[w];
    }
    __syncthreads();
    if (b >= 0) {
        int pos = wbase[wid][b] + rank;
        if (pos < BCAP) packed[(size_t)b * BCAP + pos] = val;
    }
}

// ---------------- bucket_base = exclusive prefix of tails ----------------
__global__ void k_base(const int* tails, int* bucket_base, int* rowptr, int N_) {
    __shared__ int sm[128];
    int t = threadIdx.x;   // 128 threads
    int v = (t < BKT) ? min(tails[t], BCAP) : 0;
    sm[t] = v;
    __syncthreads();
    for (int off = 1; off < 128; off <<= 1) {
        int u = (t >= off) ? sm[t - off] : 0;
        __syncthreads();
        sm[t] += u;
        __syncthreads();
    }
    if (t < BKT) bucket_base[t] = sm[t] - v;
    if (t == BKT) { bucket_base[BKT] = sm[BKT - 1]; rowptr[N_] = sm[BKT - 1]; }
}

// ---------------- per-bucket CSR build: LDS histogram + scan + scatter ------------
__global__ __launch_bounds__(1024) void k_build(const unsigned* packed, const int* tails,
                                                const int* bucket_base, int* rowptr,
                                                float* dis, int* col, int N_) {
    __shared__ int cnt[1024];
    __shared__ int pfx[1024];
    __shared__ int fill[1024];
    int b = blockIdx.x, tid = threadIdx.x;
    int nb_ = tails[b]; if (nb_ > BCAP) nb_ = BCAP;
    const unsigned* pb = packed + (size_t)b * BCAP;
    cnt[tid] = 0; fill[tid] = 0;
    __syncthreads();
    for (int s = tid; s < nb_; s += 1024)
        atomicAdd(&cnt[pb[s] >> 17], 1);
    __syncthreads();
    int v = cnt[tid];
    pfx[tid] = v;
    __syncthreads();
    for (int off = 1; off < 1024; off <<= 1) {
        int t = (tid >= off) ? pfx[tid - off] : 0;
        __syncthreads();
        pfx[tid] += t;
        __syncthreads();
    }
    int excl = pfx[tid] - v;
    int rowbase = bucket_base[b];
    int node = (b << BSHIFT) + tid;
    if (node < N_) {
        rowptr[node] = rowbase + excl;
        dis[node] = rsqrtf((float)(v + 1));
    }
    cnt[tid] = rowbase + excl;
    __syncthreads();
    for (int s = tid; s < nb_; s += 1024) {
        unsigned vv = pb[s];
        int dl = vv >> 17;
        int pos = cnt[dl] + atomicAdd(&fill[dl], 1);   // LDS atomic only
        col[pos] = (int)(vv & 131071u);
    }
}

// ---------------- g = dis[i] * (in @ W)   [N,K]@[K,64]  (R3 proven version) -------
template <int K>
__global__ __launch_bounds__(256) void k_gemm_scale(const float* __restrict__ in,
                                                    const float* __restrict__ W,
                                                    const float* __restrict__ dis,
                                                    float* __restrict__ g, int n) {
    __shared__ float wlds[K * HDIM];
    for (int i = threadIdx.x; i < K * HDIM; i += blockDim.x) wlds[i] = W[i];
    __syncthreads();
    int lane = threadIdx.x & 63;
    int wid = threadIdx.x >> 6;
    int nw = blockDim.x >> 6;
    for (int r = blockIdx.x * nw + wid; r < n; r += gridDim.x * nw) {
        const float4* xr = (const float4*)(in + (size_t)r * K);
        float acc = 0.f;
#pragma unroll
        for (int k4 = 0; k4 < K / 4; k4++) {
            float4 xv = xr[k4];
            acc = fmaf(xv.x, wlds[(k4 * 4 + 0) * HDIM + lane], acc);
            acc = fmaf(xv.y, wlds[(k4 * 4 + 1) * HDIM + lane], acc);
            acc = fmaf(xv.z, wlds[(k4 * 4 + 2) * HDIM + lane], acc);
            acc = fmaf(xv.w, wlds[(k4 * 4 + 3) * HDIM + lane], acc);
        }
        g[(size_t)r * HDIM + lane] = acc * dis[r];
    }
}

// ---------------- out[d] = [relu]( dis[d]*(g[d] + sum_e g[col[e]]) + b ) ----------
template <bool RELU>
__global__ __launch_bounds__(256) void k_aggregate(const float* __restrict__ g,
                                                   const int* __restrict__ rowptr,
                                                   const int* __restrict__ col,
                                                   const float* __restrict__ dis,
                                                   const float* __restrict__ bias,
                                                   float* __restrict__ out, int n) {
    int lane = threadIdx.x & 63;
    int wid = threadIdx.x >> 6;
    int node = blockIdx.x * (blockDim.x >> 6) + wid;
    if (node >= n) return;
    float s = g[(size_t)node * HDIM + lane];
    int e = rowptr[node], end = rowptr[node + 1];
    for (; e + 7 < end; e += 8) {
        int c0 = col[e], c1 = col[e + 1], c2 = col[e + 2], c3 = col[e + 3];
        int c4 = col[e + 4], c5 = col[e + 5], c6 = col[e + 6], c7 = col[e + 7];
        float v0 = g[(size_t)c0 * HDIM + lane];
        float v1 = g[(size_t)c1 * HDIM + lane];
        float v2 = g[(size_t)c2 * HDIM + lane];
        float v3 = g[(size_t)c3 * HDIM + lane];
        float v4 = g[(size_t)c4 * HDIM + lane];
        float v5 = g[(size_t)c5 * HDIM + lane];
        float v6 = g[(size_t)c6 * HDIM + lane];
        float v7 = g[(size_t)c7 * HDIM + lane];
        s += ((v0 + v1) + (v2 + v3)) + ((v4 + v5) + (v6 + v7));
    }
    for (; e < end; e++) s += g[(size_t)col[e] * HDIM + lane];
    float o = fmaf(dis[node], s, bias[lane]);
    if (RELU) o = fmaxf(o, 0.f);
    out[(size_t)node * HDIM + lane] = o;
}

extern "C" void kernel_launch(void* const* d_in, const int* in_sizes, int n_in,
                              void* d_out, int out_size, void* d_ws, size_t ws_size,
                              hipStream_t stream) {
    const float* x  = (const float*)d_in[0];
    const void*  ei = d_in[1];
    const float* W1 = (const float*)d_in[2];
    const float* b1 = (const float*)d_in[3];
    const float* W2 = (const float*)d_in[4];
    const float* b2 = (const float*)d_in[5];
    const float* W3 = (const float*)d_in[6];
    const float* b3 = (const float*)d_in[7];
    float* out = (float*)d_out;

    const int N = in_sizes[0] / 128;   // 100000
    const int E = in_sizes[1] / 2;     // 3200000

    char* ws = (char*)d_ws;
    auto alloc = [&](size_t bytes) {
        char* p = ws;
        ws += ((bytes + 255) / 256) * 256;
        return p;
    };
    int*   flag   = (int*)alloc(4);
    int*   tails  = (int*)alloc(BKT * 4);
    int*   bbase  = (int*)alloc((BKT + 1) * 4);
    int*   rowptr = (int*)alloc((size_t)(N + 1) * 4);
    float* dis    = (float*)alloc((size_t)N * 4);
    int*   col    = (int*)alloc((size_t)E * 4);
    float* bufA   = (float*)alloc((size_t)N * HDIM * 4);
    float* bufB   = (float*)alloc((size_t)N * HDIM * 4);
    unsigned* packed = (unsigned*)bufA;   // 98*36864*4 = 14.45 MB <= 25.6 MB

    k_detect<<<1, 128, 0, stream>>>((const unsigned*)ei, flag, tails);
    k_bucket<<<(E + 1023) / 1024, 1024, 0, stream>>>(ei, flag, tails, packed, E);
    k_base<<<1, 128, 0, stream>>>(tails, bbase, rowptr, N);
    k_build<<<BKT, 1024, 0, stream>>>(packed, tails, bbase, rowptr, dis, col, N);

    const int gemmGrid = 4096;
    const int aggGrid = (N + 3) / 4;

    k_gemm_scale<128><<<gemmGrid, 256, 0, stream>>>(x, W1, dis, bufA, N);
    k_aggregate<true><<<aggGrid, 256, 0, stream>>>(bufA, rowptr, col, dis, b1, bufB, N);
    k_gemm_scale<64><<<gemmGrid, 256, 0, stream>>>(bufB, W2, dis, bufA, N);
    k_aggregate<true><<<aggGrid, 256, 0, stream>>>(bufA, rowptr, col, dis, b2, bufB, N);
    k_gemm_scale<64><<<gemmGrid, 256, 0, stream>>>(bufB, W3, dis, bufA, N);
    k_aggregate<false><<<aggGrid, 256, 0, stream>>>(bufA, rowptr, col, dis, b3, out, N);
}